// Round 1
// baseline (1679.566 us; speedup 1.0000x reference)
//
#include <hip/hip_runtime.h>
#include <hip/hip_bf16.h>

#define NROW 16384
#define DIM 128
#define HOUT 256

typedef float f32x4 __attribute__((ext_vector_type(4)));
typedef __bf16 bf16x8 __attribute__((ext_vector_type(8)));

// ---------------- Kernel 1: features f32 [N][128] -> fT bf16 [128][N]; zero deg ----
__global__ void k_transpose(const float* __restrict__ f, short* __restrict__ fT,
                            float* __restrict__ deg) {
    __shared__ short tr[128][72];
    const int t = threadIdx.x;
    const int j0 = blockIdx.x * 64;
    if (blockIdx.x < 64) deg[blockIdx.x * 256 + t] = 0.f;   // zero 16384 floats
    // read 64 rows x 128 cols f32 (2048 float4 / 256 thr = 8 iters), transpose to LDS bf16
    for (int it = 0; it < 8; ++it) {
        int slot = t + 256 * it;
        int j = slot >> 5;          // 0..63
        int dq = slot & 31;         // d = dq*4
        f32x4 v = *reinterpret_cast<const f32x4*>(f + (size_t)(j0 + j) * DIM + dq * 4);
#pragma unroll
        for (int c = 0; c < 4; ++c) {
            __hip_bfloat16 h = __float2bfloat16(v[c]);
            tr[dq * 4 + c][j] = *reinterpret_cast<short*>(&h);
        }
    }
    __syncthreads();
    // write fT[d][j0..j0+64): 1024 x 16B / 256 thr = 4 iters
    for (int it = 0; it < 4; ++it) {
        int slot = t + 256 * it;
        int d = slot >> 3;          // 0..127
        int c8 = slot & 7;          // 8-bf16 chunk
        int4 v = *reinterpret_cast<const int4*>(&tr[d][c8 * 8]);
        *reinterpret_cast<int4*>(fT + (size_t)d * NROW + j0 + c8 * 8) = v;
    }
}

// ---------------- Kernel 2: tail partials = adj @ f (bf16 MFMA), deg row-sums -------
// grid 512: rb = bid>>1 (64-row block), s = bid&1 (K half). 256 thr = 4 waves.
__global__ __launch_bounds__(256, 2) void k_gemm(const int* __restrict__ adj,
                                                 const short* __restrict__ fT,
                                                 float* __restrict__ part,
                                                 float* __restrict__ deg) {
    __shared__ short As[64][72];    // adj tile as bf16, padded
    __shared__ short Fs[128][72];   // fT tile, padded
    const int t = threadIdx.x;
    const int rb = blockIdx.x >> 1;
    const int s  = blockIdx.x & 1;
    const int i0 = rb * 64;
    const int kb0 = s * 8192;
    const int lane = t & 63;
    const int w = t >> 6;
    const int wr = w & 1, wc = w >> 1;

    f32x4 acc[2][4] = {};
    unsigned dsum[4] = {0u, 0u, 0u, 0u};
    int4 a_reg[4], f_reg[4];

    // staging maps (fixed across steps):
    //   adj: slot=t+256*it -> row=slot>>4 (0..63), c4=slot&15 (4 int32)
    //   fT : slot=t+256*it -> d=slot>>3 (0..127), c8=slot&7 (8 bf16)
#define LOAD_TILE(kb)                                                                   \
    {                                                                                   \
        _Pragma("unroll")                                                               \
        for (int it = 0; it < 4; ++it) {                                                \
            int slot = t + 256 * it;                                                    \
            a_reg[it] = *reinterpret_cast<const int4*>(                                 \
                adj + (size_t)(i0 + (slot >> 4)) * NROW + (kb) + (slot & 15) * 4);      \
        }                                                                               \
        _Pragma("unroll")                                                               \
        for (int it = 0; it < 4; ++it) {                                                \
            int slot = t + 256 * it;                                                    \
            f_reg[it] = *reinterpret_cast<const int4*>(                                 \
                fT + (size_t)(slot >> 3) * NROW + (kb) + (slot & 7) * 8);               \
        }                                                                               \
    }

    LOAD_TILE(kb0);
    for (int step = 0; step < 128; ++step) {
        // LDS write from regs (prev MFMA finished at loop-end barrier)
#pragma unroll
        for (int it = 0; it < 4; ++it) {
            int slot = t + 256 * it;
            int row = slot >> 4, c4 = slot & 15;
            int4 v = a_reg[it];
            unsigned lo = (v.x ? 0x3F80u : 0u) | (v.y ? 0x3F800000u : 0u);
            unsigned hi = (v.z ? 0x3F80u : 0u) | (v.w ? 0x3F800000u : 0u);
            dsum[it] += (unsigned)(v.x + v.y + v.z + v.w);
            uint2 pk; pk.x = lo; pk.y = hi;
            *reinterpret_cast<uint2*>(&As[row][c4 * 4]) = pk;
        }
#pragma unroll
        for (int it = 0; it < 4; ++it) {
            int slot = t + 256 * it;
            *reinterpret_cast<int4*>(&Fs[slot >> 3][(slot & 7) * 8]) = f_reg[it];
        }
        __syncthreads();
        if (step + 1 < 128) LOAD_TILE(kb0 + (step + 1) * 64);  // in flight during MFMA
#pragma unroll
        for (int kk = 0; kk < 64; kk += 32) {
            bf16x8 af[2], bfr[4];
#pragma unroll
            for (int ti = 0; ti < 2; ++ti)
                af[ti] = *reinterpret_cast<const bf16x8*>(
                    &As[wr * 32 + ti * 16 + (lane & 15)][kk + (lane >> 4) * 8]);
#pragma unroll
            for (int ci = 0; ci < 4; ++ci)
                bfr[ci] = *reinterpret_cast<const bf16x8*>(
                    &Fs[wc * 64 + ci * 16 + (lane & 15)][kk + (lane >> 4) * 8]);
#pragma unroll
            for (int ti = 0; ti < 2; ++ti)
#pragma unroll
                for (int ci = 0; ci < 4; ++ci)
                    acc[ti][ci] = __builtin_amdgcn_mfma_f32_16x16x32_bf16(
                        af[ti], bfr[ci], acc[ti][ci], 0, 0, 0);
        }
        __syncthreads();
    }
    // store partial tail: C/D layout col=lane&15, row=(lane>>4)*4+r  [m89]
#pragma unroll
    for (int ti = 0; ti < 2; ++ti)
#pragma unroll
        for (int ci = 0; ci < 4; ++ci)
#pragma unroll
            for (int r = 0; r < 4; ++r) {
                int i = i0 + wr * 32 + ti * 16 + (lane >> 4) * 4 + r;
                int d = wc * 64 + ci * 16 + (lane & 15);
                part[((size_t)s * NROW + i) * DIM + d] = acc[ti][ci][r];
            }
    // deg reduce (reuse As as u32 scratch [64][16])
    __syncthreads();
    unsigned* degs = reinterpret_cast<unsigned*>(&As[0][0]);
#pragma unroll
    for (int it = 0; it < 4; ++it)
        degs[((t >> 4) + 16 * it) * 16 + (t & 15)] = dsum[it];
    __syncthreads();
    if (t < 64) {
        unsigned sum = 0;
#pragma unroll
        for (int c = 0; c < 16; ++c) sum += degs[t * 16 + c];
        atomicAdd(deg + i0 + t, (float)sum);
    }
}

// ---------------- Kernel 3: epilogue -------------------------------------------------
// out = tanh(f·Wo − m·(f·Wd[:, :128]) − (tail/nn)·Wd[:,128:] + bo − bd), written twice.
// grid 512 (32 rows each), 256 thr. Thread tile: 4 rows x 8 h; rt=t&7, ht=t>>3 so the
// 8 lanes sharing ht broadcast-read the same W cache lines.
__global__ __launch_bounds__(256, 2) void k_epilogue(const float* __restrict__ feat,
                                                     const float* __restrict__ part,
                                                     const float* __restrict__ deg,
                                                     const float* __restrict__ Wd,
                                                     const float* __restrict__ bd,
                                                     const float* __restrict__ Wo,
                                                     const float* __restrict__ bo,
                                                     float* __restrict__ out) {
    __shared__ float fs[32][132];
    __shared__ float tn[32][132];
    __shared__ float mrow[32], inv[32];
    const int t = threadIdx.x;
    const int i0 = blockIdx.x * 32;
    if (t < 32) {
        float d = deg[i0 + t];
        mrow[t] = d > 0.f ? 1.f : 0.f;
        inv[t]  = d > 0.f ? 1.f / d : 1.f;
    }
    __syncthreads();
    // stage fs + tn (reduce the two K-split partials, scale by 1/nn)
    for (int it = 0; it < 4; ++it) {
        int slot = t + 256 * it;
        int r = slot >> 5, dq = slot & 31;
        size_t gi = (size_t)(i0 + r) * DIM + dq * 4;
        f32x4 fv = *reinterpret_cast<const f32x4*>(feat + gi);
        *reinterpret_cast<f32x4*>(&fs[r][dq * 4]) = fv;
        f32x4 p0 = *reinterpret_cast<const f32x4*>(part + gi);
        f32x4 p1 = *reinterpret_cast<const f32x4*>(part + (size_t)NROW * DIM + gi);
        f32x4 tv = (p0 + p1) * inv[r];
        *reinterpret_cast<f32x4*>(&tn[r][dq * 4]) = tv;
    }
    __syncthreads();
    const int rt = t & 7;   // rows rt*4..+4
    const int ht = t >> 3;  // h = ht*8..+8
    float accM[4][8] = {};  // f·Wo − tn·Wd2
    float accB[4][8] = {};  // f·Wd1
    for (int d = 0; d < DIM; d += 4) {
        f32x4 fr[4], tr[4];
#pragma unroll
        for (int rr = 0; rr < 4; ++rr) {
            fr[rr] = *reinterpret_cast<const f32x4*>(&fs[rt * 4 + rr][d]);
            tr[rr] = *reinterpret_cast<const f32x4*>(&tn[rt * 4 + rr][d]);
        }
#pragma unroll
        for (int hh = 0; hh < 8; ++hh) {
            int h = ht * 8 + hh;
            f32x4 wo = *reinterpret_cast<const f32x4*>(Wo + (size_t)h * DIM + d);
            f32x4 w1 = *reinterpret_cast<const f32x4*>(Wd + (size_t)h * 2 * DIM + d);
            f32x4 w2 = *reinterpret_cast<const f32x4*>(Wd + (size_t)h * 2 * DIM + DIM + d);
#pragma unroll
            for (int rr = 0; rr < 4; ++rr)
#pragma unroll
                for (int c = 0; c < 4; ++c) {
                    accM[rr][hh] += fr[rr][c] * wo[c] - tr[rr][c] * w2[c];
                    accB[rr][hh] += fr[rr][c] * w1[c];
                }
        }
    }
    f32x4 bo0 = *reinterpret_cast<const f32x4*>(bo + ht * 8);
    f32x4 bo1 = *reinterpret_cast<const f32x4*>(bo + ht * 8 + 4);
    f32x4 bd0 = *reinterpret_cast<const f32x4*>(bd + ht * 8);
    f32x4 bd1 = *reinterpret_cast<const f32x4*>(bd + ht * 8 + 4);
#pragma unroll
    for (int rr = 0; rr < 4; ++rr) {
        int i = i0 + rt * 4 + rr;
        float m = mrow[rt * 4 + rr];
        f32x4 v0, v1;
#pragma unroll
        for (int c = 0; c < 4; ++c) {
            v0[c] = tanhf(accM[rr][c]     - m * accB[rr][c]     + bo0[c] - bd0[c]);
            v1[c] = tanhf(accM[rr][c + 4] - m * accB[rr][c + 4] + bo1[c] - bd1[c]);
        }
        float* o = out + (size_t)i * HOUT + ht * 8;
        *reinterpret_cast<f32x4*>(o) = v0;
        *reinterpret_cast<f32x4*>(o + 4) = v1;
        float* o2 = o + (size_t)NROW * HOUT;
        *reinterpret_cast<f32x4*>(o2) = v0;
        *reinterpret_cast<f32x4*>(o2 + 4) = v1;
    }
}

extern "C" void kernel_launch(void* const* d_in, const int* in_sizes, int n_in,
                              void* d_out, int out_size, void* d_ws, size_t ws_size,
                              hipStream_t stream) {
    const float* feat = (const float*)d_in[0];
    const int*   adj  = (const int*)d_in[1];
    const float* Wd   = (const float*)d_in[2];
    const float* bd   = (const float*)d_in[3];
    const float* Wo   = (const float*)d_in[4];
    const float* bo   = (const float*)d_in[5];
    float* out = (float*)d_out;
    char* ws = (char*)d_ws;
    short* fT   = (short*)ws;                              //  4 MB: [128][16384] bf16
    float* part = (float*)(ws + (size_t)4  * 1024 * 1024); // 16 MB: [2][16384][128] f32
    float* deg  = (float*)(ws + (size_t)20 * 1024 * 1024); // 64 KB
    k_transpose<<<256, 256, 0, stream>>>(feat, fT, deg);
    k_gemm     <<<512, 256, 0, stream>>>(adj, fT, part, deg);
    k_epilogue <<<512, 256, 0, stream>>>(feat, part, deg, Wd, bd, Wo, bo, out);
}

// Round 2
// 1602.419 us; speedup vs baseline: 1.0481x; 1.0481x over previous
//
#include <hip/hip_runtime.h>
#include <hip/hip_bf16.h>

#define NROW 16384
#define DIM 128
#define HOUT 256
#define SPLIT 4

typedef float f32x4 __attribute__((ext_vector_type(4)));
typedef __bf16 bf16x8 __attribute__((ext_vector_type(8)));
typedef unsigned int u32;
typedef unsigned int u32x4 __attribute__((ext_vector_type(4)));

// ---------------- Kernel 1: features f32 [N][128] -> fT bf16 [128][N]; zero deg ----
__global__ void k_transpose(const float* __restrict__ f, short* __restrict__ fT,
                            float* __restrict__ deg) {
    __shared__ short tr[128][72];
    const int t = threadIdx.x;
    const int j0 = blockIdx.x * 64;
    if (blockIdx.x < 64) deg[blockIdx.x * 256 + t] = 0.f;   // zero 16384 floats
    for (int it = 0; it < 8; ++it) {
        int slot = t + 256 * it;
        int j = slot >> 5;          // 0..63
        int dq = slot & 31;         // d = dq*4
        f32x4 v = *reinterpret_cast<const f32x4*>(f + (size_t)(j0 + j) * DIM + dq * 4);
#pragma unroll
        for (int c = 0; c < 4; ++c) {
            __hip_bfloat16 h = __float2bfloat16(v[c]);
            tr[dq * 4 + c][j] = *reinterpret_cast<short*>(&h);
        }
    }
    __syncthreads();
    for (int it = 0; it < 4; ++it) {
        int slot = t + 256 * it;
        int d = slot >> 3;          // 0..127
        int c8 = slot & 7;          // 8-bf16 chunk
        int4 v = *reinterpret_cast<const int4*>(&tr[d][c8 * 8]);
        *reinterpret_cast<int4*>(fT + (size_t)d * NROW + j0 + c8 * 8) = v;
    }
}

// ---------------- Kernel 2: streaming MFMA GEMM, no LDS, no barriers ----------------
// Fragment layouts (verified by R1 passing kernel):
//   A (16x32): lane holds row (lane&15), k = (lane>>4)*8 .. +8   (8 contiguous)
//   B (32x16): lane holds col (lane&15), k = (lane>>4)*8 .. +8
//   C (16x16): col = lane&15, row = (lane>>4)*4 + r
// Wave tile: 32 rows (2 A frags) x 128 d (8 B frags). Block: 4 waves = 128 rows.
// Grid: 128 row-blocks x SPLIT(4) K-quarters = 512 blocks. adj read exactly once.
__device__ inline bf16x8 cvt_a(const int4& a, const int4& b, int& ds) {
    union { u32x4 u; bf16x8 f; } U;
    U.u.x = (a.x ? 0x3F80u : 0u) | (a.y ? 0x3F800000u : 0u);
    U.u.y = (a.z ? 0x3F80u : 0u) | (a.w ? 0x3F800000u : 0u);
    U.u.z = (b.x ? 0x3F80u : 0u) | (b.y ? 0x3F800000u : 0u);
    U.u.w = (b.z ? 0x3F80u : 0u) | (b.w ? 0x3F800000u : 0u);
    ds += a.x + a.y + a.z + a.w + b.x + b.y + b.z + b.w;
    return U.f;
}

__global__ __launch_bounds__(256, 2) void k_gemm(const int* __restrict__ adj,
                                                 const short* __restrict__ fT,
                                                 float* __restrict__ part,
                                                 float* __restrict__ deg) {
    const int t = threadIdx.x;
    const int rb = blockIdx.x >> 2;          // 0..127: 128-row block
    const int s  = blockIdx.x & 3;           // K quarter
    const int i0 = rb * 128;
    const int kb0 = s * (NROW / SPLIT);      // 4096-wide K slice
    const int lane = t & 63;
    const int w = t >> 6;
    const int lr = lane & 15;
    const int lk = (lane >> 4) * 8;

    f32x4 acc[2][8] = {};
    int dsum[2] = {0, 0};

    const int* aptr0 = adj + (size_t)(i0 + w * 32 + lr) * NROW + kb0 + lk;
    const int* aptr1 = aptr0 + (size_t)16 * NROW;
    const short* bptr = fT + (size_t)lr * NROW + kb0 + lk;

    for (int it = 0; it < (NROW / SPLIT) / 32; ++it) {   // 128 iters, k step 32
        const int ko = it * 32;
        int4 a0a = *reinterpret_cast<const int4*>(aptr0 + ko);
        int4 a0b = *reinterpret_cast<const int4*>(aptr0 + ko + 4);
        int4 a1a = *reinterpret_cast<const int4*>(aptr1 + ko);
        int4 a1b = *reinterpret_cast<const int4*>(aptr1 + ko + 4);
        bf16x8 bf[8];
#pragma unroll
        for (int ci = 0; ci < 8; ++ci)
            bf[ci] = *reinterpret_cast<const bf16x8*>(bptr + (size_t)ci * 16 * NROW + ko);
        bf16x8 af0 = cvt_a(a0a, a0b, dsum[0]);
        bf16x8 af1 = cvt_a(a1a, a1b, dsum[1]);
#pragma unroll
        for (int ci = 0; ci < 8; ++ci) {
            acc[0][ci] = __builtin_amdgcn_mfma_f32_16x16x32_bf16(af0, bf[ci], acc[0][ci], 0, 0, 0);
            acc[1][ci] = __builtin_amdgcn_mfma_f32_16x16x32_bf16(af1, bf[ci], acc[1][ci], 0, 0, 0);
        }
    }
    // store partials
#pragma unroll
    for (int ti = 0; ti < 2; ++ti)
#pragma unroll
        for (int ci = 0; ci < 8; ++ci)
#pragma unroll
            for (int r = 0; r < 4; ++r) {
                int i = i0 + w * 32 + ti * 16 + (lane >> 4) * 4 + r;
                int d = ci * 16 + lr;
                part[((size_t)s * NROW + i) * DIM + d] = acc[ti][ci][r];
            }
    // deg: lane's dsum covers k-slice (lane>>4); union over lanes {lr, lr+16, +32, +48}
#pragma unroll
    for (int ti = 0; ti < 2; ++ti) {
        float v = (float)dsum[ti];
        v += __shfl_xor(v, 16);
        v += __shfl_xor(v, 32);
        if (lane < 16) atomicAdd(deg + i0 + w * 32 + ti * 16 + lr, v);
    }
}

// ---------------- Kernel 3: epilogue -------------------------------------------------
// out = tanh(f·Wo − m·(f·Wd[:, :128]) − (tail/nn)·Wd[:,128:] + bo − bd), written twice.
__global__ __launch_bounds__(256, 2) void k_epilogue(const float* __restrict__ feat,
                                                     const float* __restrict__ part,
                                                     const float* __restrict__ deg,
                                                     const float* __restrict__ Wd,
                                                     const float* __restrict__ bd,
                                                     const float* __restrict__ Wo,
                                                     const float* __restrict__ bo,
                                                     float* __restrict__ out) {
    __shared__ float fs[32][132];
    __shared__ float tn[32][132];
    __shared__ float mrow[32], inv[32];
    const int t = threadIdx.x;
    const int i0 = blockIdx.x * 32;
    if (t < 32) {
        float d = deg[i0 + t];
        mrow[t] = d > 0.f ? 1.f : 0.f;
        inv[t]  = d > 0.f ? 1.f / d : 1.f;
    }
    __syncthreads();
    for (int it = 0; it < 4; ++it) {
        int slot = t + 256 * it;
        int r = slot >> 5, dq = slot & 31;
        size_t gi = (size_t)(i0 + r) * DIM + dq * 4;
        f32x4 fv = *reinterpret_cast<const f32x4*>(feat + gi);
        *reinterpret_cast<f32x4*>(&fs[r][dq * 4]) = fv;
        f32x4 p = *reinterpret_cast<const f32x4*>(part + gi);
#pragma unroll
        for (int sp = 1; sp < SPLIT; ++sp)
            p += *reinterpret_cast<const f32x4*>(part + (size_t)sp * NROW * DIM + gi);
        f32x4 tv = p * inv[r];
        *reinterpret_cast<f32x4*>(&tn[r][dq * 4]) = tv;
    }
    __syncthreads();
    const int rt = t & 7;   // rows rt*4..+4
    const int ht = t >> 3;  // h = ht*8..+8
    float accM[4][8] = {};  // f·Wo − tn·Wd2
    float accB[4][8] = {};  // f·Wd1
    for (int d = 0; d < DIM; d += 4) {
        f32x4 fr[4], tr[4];
#pragma unroll
        for (int rr = 0; rr < 4; ++rr) {
            fr[rr] = *reinterpret_cast<const f32x4*>(&fs[rt * 4 + rr][d]);
            tr[rr] = *reinterpret_cast<const f32x4*>(&tn[rt * 4 + rr][d]);
        }
#pragma unroll
        for (int hh = 0; hh < 8; ++hh) {
            int h = ht * 8 + hh;
            f32x4 wo = *reinterpret_cast<const f32x4*>(Wo + (size_t)h * DIM + d);
            f32x4 w1 = *reinterpret_cast<const f32x4*>(Wd + (size_t)h * 2 * DIM + d);
            f32x4 w2 = *reinterpret_cast<const f32x4*>(Wd + (size_t)h * 2 * DIM + DIM + d);
#pragma unroll
            for (int rr = 0; rr < 4; ++rr)
#pragma unroll
                for (int c = 0; c < 4; ++c) {
                    accM[rr][hh] += fr[rr][c] * wo[c] - tr[rr][c] * w2[c];
                    accB[rr][hh] += fr[rr][c] * w1[c];
                }
        }
    }
    f32x4 bo0 = *reinterpret_cast<const f32x4*>(bo + ht * 8);
    f32x4 bo1 = *reinterpret_cast<const f32x4*>(bo + ht * 8 + 4);
    f32x4 bd0 = *reinterpret_cast<const f32x4*>(bd + ht * 8);
    f32x4 bd1 = *reinterpret_cast<const f32x4*>(bd + ht * 8 + 4);
#pragma unroll
    for (int rr = 0; rr < 4; ++rr) {
        int i = i0 + rt * 4 + rr;
        float m = mrow[rt * 4 + rr];
        f32x4 v0, v1;
#pragma unroll
        for (int c = 0; c < 4; ++c) {
            v0[c] = tanhf(accM[rr][c]     - m * accB[rr][c]     + bo0[c] - bd0[c]);
            v1[c] = tanhf(accM[rr][c + 4] - m * accB[rr][c + 4] + bo1[c] - bd1[c]);
        }
        float* o = out + (size_t)i * HOUT + ht * 8;
        *reinterpret_cast<f32x4*>(o) = v0;
        *reinterpret_cast<f32x4*>(o + 4) = v1;
        float* o2 = o + (size_t)NROW * HOUT;
        *reinterpret_cast<f32x4*>(o2) = v0;
        *reinterpret_cast<f32x4*>(o2 + 4) = v1;
    }
}

extern "C" void kernel_launch(void* const* d_in, const int* in_sizes, int n_in,
                              void* d_out, int out_size, void* d_ws, size_t ws_size,
                              hipStream_t stream) {
    const float* feat = (const float*)d_in[0];
    const int*   adj  = (const int*)d_in[1];
    const float* Wd   = (const float*)d_in[2];
    const float* bd   = (const float*)d_in[3];
    const float* Wo   = (const float*)d_in[4];
    const float* bo   = (const float*)d_in[5];
    float* out = (float*)d_out;
    char* ws = (char*)d_ws;
    short* fT   = (short*)ws;                              //  4 MB: [128][16384] bf16
    float* part = (float*)(ws + (size_t)4  * 1024 * 1024); // 33.5 MB: [4][16384][128] f32
    float* deg  = (float*)(ws + (size_t)40 * 1024 * 1024); // 64 KB
    k_transpose<<<256, 256, 0, stream>>>(feat, fT, deg);
    k_gemm     <<<512, 256, 0, stream>>>(adj, fT, part, deg);
    k_epilogue <<<512, 256, 0, stream>>>(feat, part, deg, Wd, bd, Wo, bo, out);
}